// Round 10
// baseline (581.391 us; speedup 1.0000x reference)
//
#include <hip/hip_runtime.h>

// GCN 2-layer forward. Round 10: partition-sorted edges are aggregated
// DIRECTLY from the pairs window into per-partition LDS f32 accumulators
// (256 nodes x F fit in LDS) via ds_add_f32 — no CSR finalize, no per-node
// gather walk. MFMA GEMMs (bf16 split), bf16 feature tables.

#define F1 64
#define F2 16
#define G 256      // chunk blocks for partition passes
#define HP 256     // partition stride; partition = dst >> 8; npart <= 256 (n <= 65536)

typedef __attribute__((ext_vector_type(8))) short bf16x8;
typedef __attribute__((ext_vector_type(4))) float f32x4;
typedef __attribute__((ext_vector_type(4))) unsigned short u16x4;

// f32 -> bf16 round-to-nearest-even
__device__ inline unsigned short f2bf(float f) {
    unsigned u = __float_as_uint(f);
    return (unsigned short)((u + 0x7FFFu + ((u >> 16) & 1u)) >> 16);
}
__device__ inline float bf2f(unsigned short s) {
    return __uint_as_float(((unsigned)s) << 16);
}

// split 8 f32 into hi/lo bf16 (truncation split: hi exact-high, lo ~2^-17 rel)
__device__ inline void cvt8(const float* v, bf16x8& h, bf16x8& l) {
#pragma unroll
    for (int i = 0; i < 8; ++i) {
        unsigned b = __float_as_uint(v[i]);
        h[i] = (short)(b >> 16);
        float hif = __uint_as_float(b & 0xFFFF0000u);
        float lof = v[i] - hif;
        l[i] = (short)(__float_as_uint(lof) >> 16);
    }
}

// ---------------- CSR-lite build ----------------

// P1: per-chunk histogram over partitions + global per-node degree counts
__global__ __launch_bounds__(256) void k_hist(const int4* __restrict__ dst4,
                                              const int* __restrict__ dst,
                                              int* __restrict__ hist,
                                              int* __restrict__ cnt, int e4, int e) {
    __shared__ int hl[HP];
    int tid = threadIdx.x, g = blockIdx.x;
    hl[tid] = 0;
    __syncthreads();
    int chunk = (e4 + G - 1) / G;
    int beg = g * chunk, end = min(e4, beg + chunk);
    for (int i = beg + tid; i < end; i += 256) {
        int4 d = dst4[i];
        atomicAdd(&hl[d.x >> 8], 1);
        atomicAdd(&hl[d.y >> 8], 1);
        atomicAdd(&hl[d.z >> 8], 1);
        atomicAdd(&hl[d.w >> 8], 1);
        atomicAdd(&cnt[d.x], 1);
        atomicAdd(&cnt[d.y], 1);
        atomicAdd(&cnt[d.z], 1);
        atomicAdd(&cnt[d.w], 1);
    }
    if (g == G - 1)
        for (int i = e4 * 4 + tid; i < e; i += 256) {
            int d = dst[i];
            atomicAdd(&hl[d >> 8], 1);
            atomicAdd(&cnt[d], 1);
        }
    __syncthreads();
    hist[g * HP + tid] = hl[tid];
}

// P2: per-partition scan over chunks -> local offsets + partition totals.
// Blocks >= npart compute dinv from cnt (independent work, stuffed).
__global__ __launch_bounds__(256) void k_cscan(const int* __restrict__ hist,
                                               int* __restrict__ pgoff,
                                               int* __restrict__ ptotal,
                                               const int* __restrict__ cnt,
                                               float* __restrict__ dinv,
                                               int n, int npart) {
    if ((int)blockIdx.x >= npart) {
        int i = ((int)blockIdx.x - npart) * 256 + threadIdx.x;
        if (i < n) dinv[i] = rsqrtf((float)cnt[i] + 1.0f);  // +1 self loop
        return;
    }
    __shared__ int s[G];
    int p = blockIdx.x, g = threadIdx.x;
    int v = hist[g * HP + p];
    s[g] = v;
    __syncthreads();
    for (int off = 1; off < G; off <<= 1) {
        int t = (g >= off) ? s[g - off] : 0;
        __syncthreads();
        s[g] += t;
        __syncthreads();
    }
    pgoff[g * HP + p] = s[g] - v;  // chunk-local exclusive
    if (g == G - 1) ptotal[p] = s[g];
}

// P3 + GEMM1 fused (independent work, block-range branch).
// blocks [0, nb1): h_bf = bf16(x @ W1)   (MFMA, 3-term split)
// blocks [nb1, nb1+G): partition scatter into packed pairs
__global__ __launch_bounds__(256) void k_pm1(const float* __restrict__ x,
                                             const float* __restrict__ W1,
                                             unsigned short* __restrict__ h_bf,
                                             const int4* __restrict__ src4,
                                             const int4* __restrict__ dst4,
                                             const int* __restrict__ src,
                                             const int* __restrict__ dst,
                                             const int* __restrict__ pgoff,
                                             const int* __restrict__ ptotal,
                                             unsigned* __restrict__ pairs,
                                             int e4, int e, int npart,
                                             int n, int nb1) {
    __shared__ float ws[64 * 65];        // mgemm1 branch
    __shared__ int s[HP], cur[HP];       // part branch
    int tid = threadIdx.x;
    if ((int)blockIdx.x < nb1) {
        // ---- mgemm1 ----
        for (int i = tid; i < 64 * 64; i += 256) {
            int k = i >> 6, c = i & 63;
            ws[k * 65 + c] = W1[i];
        }
        __syncthreads();
        int lane = tid & 63, wv = tid >> 6;
        int rt = blockIdx.x * 64 + wv * 16;
        int r = lane & 15, g = lane >> 4;
        int row = rt + r;
        int rowc = row < n ? row : n - 1;
        const float* xp = x + (size_t)rowc * F1 + g * 8;
        bf16x8 ah[2], al[2];
#pragma unroll
        for (int kb = 0; kb < 2; ++kb) {
            float v[8];
            *(float4*)&v[0] = *(const float4*)(xp + kb * 32);
            *(float4*)&v[4] = *(const float4*)(xp + kb * 32 + 4);
            cvt8(v, ah[kb], al[kb]);
        }
#pragma unroll
        for (int ct = 0; ct < 4; ++ct) {
            bf16x8 bh[2], bl[2];
#pragma unroll
            for (int kb = 0; kb < 2; ++kb) {
                float v[8];
#pragma unroll
                for (int i = 0; i < 8; ++i)
                    v[i] = ws[(kb * 32 + g * 8 + i) * 65 + ct * 16 + r];
                cvt8(v, bh[kb], bl[kb]);
            }
            f32x4 acc = {0.f, 0.f, 0.f, 0.f};
#pragma unroll
            for (int kb = 0; kb < 2; ++kb) {
                acc = __builtin_amdgcn_mfma_f32_16x16x32_bf16(ah[kb], bh[kb], acc, 0, 0, 0);
                acc = __builtin_amdgcn_mfma_f32_16x16x32_bf16(al[kb], bh[kb], acc, 0, 0, 0);
                acc = __builtin_amdgcn_mfma_f32_16x16x32_bf16(ah[kb], bl[kb], acc, 0, 0, 0);
            }
#pragma unroll
            for (int j = 0; j < 4; ++j) {
                int orow = rt + g * 4 + j;
                if (orow < n) h_bf[(size_t)orow * F1 + ct * 16 + r] = f2bf(acc[j]);
            }
        }
    } else {
        // ---- part ----
        int g = blockIdx.x - nb1;
        int v = (tid < npart) ? ptotal[tid] : 0;
        s[tid] = v;
        __syncthreads();
        for (int off = 1; off < HP; off <<= 1) {
            int t = (tid >= off) ? s[tid - off] : 0;
            __syncthreads();
            s[tid] += t;
            __syncthreads();
        }
        cur[tid] = (s[tid] - v) + pgoff[g * HP + tid];  // part_base + chunk offset
        __syncthreads();
        int chunk = (e4 + G - 1) / G;
        int beg = g * chunk, end = min(e4, beg + chunk);
        for (int i = beg + tid; i < end; i += 256) {
            int4 s4 = src4[i];
            int4 d4 = dst4[i];
            int pos;
            pos = atomicAdd(&cur[d4.x >> 8], 1); pairs[pos] = ((unsigned)(d4.x & 255) << 16) | (unsigned)s4.x;
            pos = atomicAdd(&cur[d4.y >> 8], 1); pairs[pos] = ((unsigned)(d4.y & 255) << 16) | (unsigned)s4.y;
            pos = atomicAdd(&cur[d4.z >> 8], 1); pairs[pos] = ((unsigned)(d4.z & 255) << 16) | (unsigned)s4.z;
            pos = atomicAdd(&cur[d4.w >> 8], 1); pairs[pos] = ((unsigned)(d4.w & 255) << 16) | (unsigned)s4.w;
        }
        if (g == G - 1)
            for (int i = e4 * 4 + tid; i < e; i += 256) {
                int d = dst[i];
                int pos = atomicAdd(&cur[d >> 8], 1);
                pairs[pos] = ((unsigned)(d & 255) << 16) | (unsigned)src[i];
            }
    }
}

// ---------------- Streamed partition aggregation (LDS f32 atomics) ----------------

// Layer 1: block p streams its pairs window; facc[256][64] in LDS.
// Epilogue fuses self-loop + b1 + relu + bf16 -> a1b.
__global__ __launch_bounds__(512) void k_pagg64(const unsigned* __restrict__ pairs,
                                                const int* __restrict__ ptotal,
                                                const float* __restrict__ dinv,
                                                const unsigned short* __restrict__ hb,
                                                const float* __restrict__ b1,
                                                unsigned short* __restrict__ a1b,
                                                int n, int npart) {
    __shared__ __align__(16) float facc[256 * F1];   // 64 KB
    __shared__ int swin[HP];
    __shared__ float sdinv[256];
    __shared__ int wbs, wes;
    int p = blockIdx.x, tid = threadIdx.x;
    // window = [part_base[p], part_base[p+1]) via LDS scan of ptotal
    int v = (tid < HP && tid < npart) ? ptotal[tid] : 0;
    if (tid < HP) swin[tid] = v;
    __syncthreads();
    for (int off = 1; off < HP; off <<= 1) {
        int t = (tid >= off && tid < HP) ? swin[tid - off] : 0;
        __syncthreads();
        if (tid < HP) swin[tid] += t;
        __syncthreads();
    }
    if (tid == p) { wbs = swin[tid] - v; wes = swin[tid]; }
    if (tid < 256) {
        int node = (p << 8) + tid;
        sdinv[tid] = (node < n) ? dinv[node] : 0.f;
    }
    for (int i = tid; i < 256 * (F1 / 4); i += 512)
        ((float4*)facc)[i] = make_float4(0.f, 0.f, 0.f, 0.f);
    __syncthreads();
    int wbeg = wbs, wend = wes;
    int lane = tid & 63, wv = tid >> 6;   // 8 waves; wave = one edge, lane = feat
    for (int i = wbeg + wv; i < wend; i += 8) {
        unsigned u = pairs[i];
        int dl = u >> 16;
        int s = (int)(u & 0xFFFFu);
        float w = dinv[s] * sdinv[dl];
        float hv = bf2f(hb[(size_t)s * F1 + lane]);
        atomicAdd(&facc[dl * F1 + lane], w * hv);   // ds_add_f32, 2-way bank alias (free)
    }
    __syncthreads();
    // epilogue: self-loop + bias1 + relu + bf16
    float bl = b1[lane];
    for (int nd = wv; nd < 256; nd += 8) {
        int node = (p << 8) + nd;
        if (node < n) {
            float di = sdinv[nd];
            float self = bf2f(hb[(size_t)node * F1 + lane]);
            float o = fmaxf(fmaf(di * di, self, facc[nd * F1 + lane]) + bl, 0.f);
            a1b[(size_t)node * F1 + lane] = f2bf(o);
        }
    }
}

// Layer 2: facc[256][16]; epilogue fuses self-loop + b2 + log-softmax -> out.
__global__ __launch_bounds__(512) void k_pagg16(const unsigned* __restrict__ pairs,
                                                const int* __restrict__ ptotal,
                                                const float* __restrict__ dinv,
                                                const unsigned short* __restrict__ h2b,
                                                const float* __restrict__ b2,
                                                float* __restrict__ out,
                                                int n, int npart) {
    __shared__ __align__(16) float facc[256 * F2];   // 16 KB
    __shared__ int swin[HP];
    __shared__ float sdinv[256];
    __shared__ int wbs, wes;
    int p = blockIdx.x, tid = threadIdx.x;
    int v = (tid < HP && tid < npart) ? ptotal[tid] : 0;
    if (tid < HP) swin[tid] = v;
    __syncthreads();
    for (int off = 1; off < HP; off <<= 1) {
        int t = (tid >= off && tid < HP) ? swin[tid - off] : 0;
        __syncthreads();
        if (tid < HP) swin[tid] += t;
        __syncthreads();
    }
    if (tid == p) { wbs = swin[tid] - v; wes = swin[tid]; }
    if (tid < 256) {
        int node = (p << 8) + tid;
        sdinv[tid] = (node < n) ? dinv[node] : 0.f;
    }
    for (int i = tid; i < 256 * (F2 / 4); i += 512)
        ((float4*)facc)[i] = make_float4(0.f, 0.f, 0.f, 0.f);
    __syncthreads();
    int wbeg = wbs, wend = wes;
    int f = tid & 15, grp = tid >> 4;   // 32 groups of 16 lanes; group = one edge
    for (int i = wbeg + grp; i < wend; i += 32) {
        unsigned u = pairs[i];
        int dl = u >> 16;
        int s = (int)(u & 0xFFFFu);
        float w = dinv[s] * sdinv[dl];
        float hv = bf2f(h2b[(size_t)s * F2 + f]);
        atomicAdd(&facc[dl * F2 + f], w * hv);
    }
    __syncthreads();
    // epilogue: self-loop + bias2 + log-softmax (16-lane groups)
    float bf = b2[f];
#pragma unroll
    for (int pass = 0; pass < 8; ++pass) {
        int nd = pass * 32 + grp;
        int node = (p << 8) + nd;
        if (node < n) {
            float di = sdinv[nd];
            float self = bf2f(h2b[(size_t)node * F2 + f]);
            float vv = fmaf(di * di, self, facc[nd * F2 + f]) + bf;
            float mr = vv;
            for (int o = 1; o < 16; o <<= 1) mr = fmaxf(mr, __shfl_xor(mr, o, 16));
            float ex = expf(vv - mr);
            float sm = ex;
            for (int o = 1; o < 16; o <<= 1) sm += __shfl_xor(sm, o, 16);
            out[(size_t)node * F2 + f] = vv - mr - logf(sm);
        }
    }
}

// h2_bf = bf16( a1b @ W2 ); A is pre-activated bf16 (bias1+relu fused upstream)
__global__ __launch_bounds__(256) void k_mgemm2(const unsigned short* __restrict__ a1b,
                                                const float* __restrict__ W2,
                                                unsigned short* __restrict__ h2_bf, int n) {
    __shared__ float ws[64 * 17];
    int tid = threadIdx.x;
    for (int i = tid; i < 64 * 16; i += 256) {
        int k = i >> 4, c = i & 15;
        ws[k * 17 + c] = W2[i];
    }
    __syncthreads();
    int lane = tid & 63, wv = tid >> 6;
    int rt = blockIdx.x * 64 + wv * 16;
    int r = lane & 15, g = lane >> 4;
    int row = rt + r;
    int rowc = row < n ? row : n - 1;
    const unsigned short* ap = a1b + (size_t)rowc * F1 + g * 8;
    bf16x8 ah[2];
    ah[0] = *(const bf16x8*)(ap);
    ah[1] = *(const bf16x8*)(ap + 32);
    bf16x8 bh[2], bl[2];
#pragma unroll
    for (int kb = 0; kb < 2; ++kb) {
        float v[8];
#pragma unroll
        for (int i = 0; i < 8; ++i)
            v[i] = ws[(kb * 32 + g * 8 + i) * 17 + r];
        cvt8(v, bh[kb], bl[kb]);
    }
    f32x4 acc = {0.f, 0.f, 0.f, 0.f};
#pragma unroll
    for (int kb = 0; kb < 2; ++kb) {
        acc = __builtin_amdgcn_mfma_f32_16x16x32_bf16(ah[kb], bh[kb], acc, 0, 0, 0);
        acc = __builtin_amdgcn_mfma_f32_16x16x32_bf16(ah[kb], bl[kb], acc, 0, 0, 0);
    }
#pragma unroll
    for (int j = 0; j < 4; ++j) {
        int orow = rt + g * 4 + j;
        if (orow < n) h2_bf[(size_t)orow * F2 + r] = f2bf(acc[j]);
    }
}

extern "C" void kernel_launch(void* const* d_in, const int* in_sizes, int n_in,
                              void* d_out, int out_size, void* d_ws, size_t ws_size,
                              hipStream_t stream) {
    const float* x  = (const float*)d_in[0];
    const int*   ei = (const int*)d_in[1];
    const float* W1 = (const float*)d_in[2];
    const float* b1 = (const float*)d_in[3];
    const float* W2 = (const float*)d_in[4];
    const float* b2 = (const float*)d_in[5];
    float* out = (float*)d_out;

    const int n = in_sizes[0] / F1;   // 50000
    const int e = in_sizes[1] / 2;    // 800000
    const int e4 = e >> 2;
    const int* src = ei;
    const int* dst = ei + e;

    const int na = (n + 63) & ~63;
    const int npart = (n + 255) >> 8;      // 196 (<=256 for n<=65536)
    const int nb1 = (n + 63) / 64;         // mgemm1 blocks (782)
    const int ndb = (n + 255) / 256;       // dinv blocks (196)

    // ws layout (4B units):
    // dinv[na] | cnt[na] | ptotal[256] | h_bf[n*64 u16] | a1b[n*64 u16]
    // | hist[G*HP] | pgoff[G*HP] | pairs[e]
    float* dinv     = (float*)d_ws;
    int* cnt        = (int*)(dinv + na);
    int* ptotal     = cnt + na;
    unsigned short* h_bf = (unsigned short*)(ptotal + 256);
    unsigned short* a1b  = h_bf + (size_t)n * F1;
    int* hist       = (int*)(a1b + (size_t)n * F1);
    int* pgoff      = hist + G * HP;
    unsigned* pairs = (unsigned*)(pgoff + G * HP);
    unsigned short* h2_bf = h_bf;  // layer-2 reuse (h_bf dead after pagg64)

    // ---- build ----
    hipMemsetAsync(cnt, 0, (size_t)n * sizeof(int), stream);
    k_hist <<<G, 256, 0, stream>>>((const int4*)dst, dst, hist, cnt, e4, e);
    k_cscan<<<npart + ndb, 256, 0, stream>>>(hist, pgoff, ptotal, cnt, dinv, n, npart);
    k_pm1  <<<nb1 + G, 256, 0, stream>>>(x, W1, h_bf,
                                         (const int4*)src, (const int4*)dst, src, dst,
                                         pgoff, ptotal, pairs, e4, e, npart, n, nb1);

    // ---- layer 1 aggregation (streamed, LDS atomics; fused b1+relu+bf16) ----
    k_pagg64<<<npart, 512, 0, stream>>>(pairs, ptotal, dinv, h_bf, b1, a1b, n, npart);

    // ---- layer 2 ----
    k_mgemm2<<<(n + 63) / 64, 256, 0, stream>>>(a1b, W2, h2_bf, n);
    k_pagg16<<<npart, 512, 0, stream>>>(pairs, ptotal, dinv, h2_bf, b2, out, n, npart);
}

// Round 13
// 161.935 us; speedup vs baseline: 3.5903x; 3.5903x over previous
//
#include <hip/hip_runtime.h>

// GCN 2-layer forward. Round 11 = round-9 structure (proven 150.5us) with
// widened aggregation gathers: u16x8 (16B/lane), 8 edge-slots (L1) / 32
// edge-slots (L2) per wave -> 2x in-flight gathers, half the load/shfl instrs.

#define F1 64
#define F2 16
#define G 256      // chunk blocks for partition passes
#define HP 256     // partition stride; partition = dst >> 8; npart <= 256 (n <= 65536)

typedef __attribute__((ext_vector_type(8))) short bf16x8;
typedef __attribute__((ext_vector_type(4))) float f32x4;
typedef __attribute__((ext_vector_type(4))) unsigned short u16x4;
typedef __attribute__((ext_vector_type(8))) unsigned short u16x8;

// f32 -> bf16 round-to-nearest-even
__device__ inline unsigned short f2bf(float f) {
    unsigned u = __float_as_uint(f);
    return (unsigned short)((u + 0x7FFFu + ((u >> 16) & 1u)) >> 16);
}
__device__ inline float bf2f(unsigned short s) {
    return __uint_as_float(((unsigned)s) << 16);
}

// split 8 f32 into hi/lo bf16 (truncation split: hi exact-high, lo ~2^-17 rel)
__device__ inline void cvt8(const float* v, bf16x8& h, bf16x8& l) {
#pragma unroll
    for (int i = 0; i < 8; ++i) {
        unsigned b = __float_as_uint(v[i]);
        h[i] = (short)(b >> 16);
        float hif = __uint_as_float(b & 0xFFFF0000u);
        float lof = v[i] - hif;
        l[i] = (short)(__float_as_uint(lof) >> 16);
    }
}

// ---------------- CSR build ----------------

// P1: per-chunk histogram over partitions
__global__ __launch_bounds__(256) void k_hist(const int4* __restrict__ dst4,
                                              const int* __restrict__ dst,
                                              int* __restrict__ hist, int e4, int e) {
    __shared__ int hl[HP];
    int tid = threadIdx.x, g = blockIdx.x;
    hl[tid] = 0;
    __syncthreads();
    int chunk = (e4 + G - 1) / G;
    int beg = g * chunk, end = min(e4, beg + chunk);
    for (int i = beg + tid; i < end; i += 256) {
        int4 d = dst4[i];
        atomicAdd(&hl[d.x >> 8], 1);
        atomicAdd(&hl[d.y >> 8], 1);
        atomicAdd(&hl[d.z >> 8], 1);
        atomicAdd(&hl[d.w >> 8], 1);
    }
    if (g == G - 1)
        for (int i = e4 * 4 + tid; i < e; i += 256) atomicAdd(&hl[dst[i] >> 8], 1);
    __syncthreads();
    hist[g * HP + tid] = hl[tid];
}

// P2: per-partition scan over chunks -> local offsets + partition totals
__global__ __launch_bounds__(256) void k_cscan(const int* __restrict__ hist,
                                               int* __restrict__ pgoff,
                                               int* __restrict__ ptotal) {
    __shared__ int s[G];
    int p = blockIdx.x, g = threadIdx.x;
    int v = hist[g * HP + p];
    s[g] = v;
    __syncthreads();
    for (int off = 1; off < G; off <<= 1) {
        int t = (g >= off) ? s[g - off] : 0;
        __syncthreads();
        s[g] += t;
        __syncthreads();
    }
    pgoff[g * HP + p] = s[g] - v;  // chunk-local exclusive
    if (g == G - 1) ptotal[p] = s[g];
}

// P3 + GEMM1 fused (independent work, block-range branch).
// blocks [0, nb1): h_bf = bf16(x @ W1)   (MFMA, 3-term split)
// blocks [nb1, nb1+G): partition scatter into packed pairs
__global__ __launch_bounds__(256) void k_pm1(const float* __restrict__ x,
                                             const float* __restrict__ W1,
                                             unsigned short* __restrict__ h_bf,
                                             const int4* __restrict__ src4,
                                             const int4* __restrict__ dst4,
                                             const int* __restrict__ src,
                                             const int* __restrict__ dst,
                                             const int* __restrict__ pgoff,
                                             const int* __restrict__ ptotal,
                                             unsigned* __restrict__ pairs,
                                             int e4, int e, int npart,
                                             int n, int nb1) {
    __shared__ float ws[64 * 65];        // mgemm1 branch
    __shared__ int s[HP], cur[HP];       // part branch
    int tid = threadIdx.x;
    if ((int)blockIdx.x < nb1) {
        // ---- mgemm1 ----
        for (int i = tid; i < 64 * 64; i += 256) {
            int k = i >> 6, c = i & 63;
            ws[k * 65 + c] = W1[i];
        }
        __syncthreads();
        int lane = tid & 63, wv = tid >> 6;
        int rt = blockIdx.x * 64 + wv * 16;
        int r = lane & 15, g = lane >> 4;
        int row = rt + r;
        int rowc = row < n ? row : n - 1;
        const float* xp = x + (size_t)rowc * F1 + g * 8;
        bf16x8 ah[2], al[2];
#pragma unroll
        for (int kb = 0; kb < 2; ++kb) {
            float v[8];
            *(float4*)&v[0] = *(const float4*)(xp + kb * 32);
            *(float4*)&v[4] = *(const float4*)(xp + kb * 32 + 4);
            cvt8(v, ah[kb], al[kb]);
        }
#pragma unroll
        for (int ct = 0; ct < 4; ++ct) {
            bf16x8 bh[2], bl[2];
#pragma unroll
            for (int kb = 0; kb < 2; ++kb) {
                float v[8];
#pragma unroll
                for (int i = 0; i < 8; ++i)
                    v[i] = ws[(kb * 32 + g * 8 + i) * 65 + ct * 16 + r];
                cvt8(v, bh[kb], bl[kb]);
            }
            f32x4 acc = {0.f, 0.f, 0.f, 0.f};
#pragma unroll
            for (int kb = 0; kb < 2; ++kb) {
                acc = __builtin_amdgcn_mfma_f32_16x16x32_bf16(ah[kb], bh[kb], acc, 0, 0, 0);
                acc = __builtin_amdgcn_mfma_f32_16x16x32_bf16(al[kb], bh[kb], acc, 0, 0, 0);
                acc = __builtin_amdgcn_mfma_f32_16x16x32_bf16(ah[kb], bl[kb], acc, 0, 0, 0);
            }
#pragma unroll
            for (int j = 0; j < 4; ++j) {
                int orow = rt + g * 4 + j;
                if (orow < n) h_bf[(size_t)orow * F1 + ct * 16 + r] = f2bf(acc[j]);
            }
        }
    } else {
        // ---- part ----
        int g = blockIdx.x - nb1;
        int v = (tid < npart) ? ptotal[tid] : 0;
        s[tid] = v;
        __syncthreads();
        for (int off = 1; off < HP; off <<= 1) {
            int t = (tid >= off) ? s[tid - off] : 0;
            __syncthreads();
            s[tid] += t;
            __syncthreads();
        }
        cur[tid] = (s[tid] - v) + pgoff[g * HP + tid];  // part_base + chunk offset
        __syncthreads();
        int chunk = (e4 + G - 1) / G;
        int beg = g * chunk, end = min(e4, beg + chunk);
        for (int i = beg + tid; i < end; i += 256) {
            int4 s4 = src4[i];
            int4 d4 = dst4[i];
            int pos;
            pos = atomicAdd(&cur[d4.x >> 8], 1); pairs[pos] = ((unsigned)(d4.x & 255) << 16) | (unsigned)s4.x;
            pos = atomicAdd(&cur[d4.y >> 8], 1); pairs[pos] = ((unsigned)(d4.y & 255) << 16) | (unsigned)s4.y;
            pos = atomicAdd(&cur[d4.z >> 8], 1); pairs[pos] = ((unsigned)(d4.z & 255) << 16) | (unsigned)s4.z;
            pos = atomicAdd(&cur[d4.w >> 8], 1); pairs[pos] = ((unsigned)(d4.w & 255) << 16) | (unsigned)s4.w;
        }
        if (g == G - 1)
            for (int i = e4 * 4 + tid; i < e; i += 256) {
                int d = dst[i];
                int pos = atomicAdd(&cur[d >> 8], 1);
                pairs[pos] = ((unsigned)(d & 255) << 16) | (unsigned)src[i];
            }
    }
}

// P4: per-partition bucket sort -> csr; fuses rowstart + dinv
__global__ __launch_bounds__(256) void k_csr(const unsigned* __restrict__ pairs,
                                             const int* __restrict__ ptotal,
                                             int* __restrict__ rowstart,
                                             float* __restrict__ dinv,
                                             int* __restrict__ csr,
                                             int n, int e, int npart) {
    __shared__ int s[HP];
    __shared__ int cnt[256], cur[256];
    __shared__ int wbs, wes;
    int p = blockIdx.x, tid = threadIdx.x;
    int v = (tid < npart) ? ptotal[tid] : 0;
    s[tid] = v;
    __syncthreads();
    for (int off = 1; off < HP; off <<= 1) {
        int t = (tid >= off) ? s[tid - off] : 0;
        __syncthreads();
        s[tid] += t;
        __syncthreads();
    }
    if (tid == p) { wbs = s[tid] - v; wes = s[tid]; }
    cnt[tid] = 0;
    __syncthreads();
    int wbeg = wbs, wend = wes;
    for (int i = wbeg + tid; i < wend; i += 256)
        atomicAdd(&cnt[pairs[i] >> 16], 1);
    __syncthreads();
    int c = cnt[tid];
    s[tid] = c;
    __syncthreads();
    for (int off = 1; off < 256; off <<= 1) {
        int t = (tid >= off) ? s[tid - off] : 0;
        __syncthreads();
        s[tid] += t;
        __syncthreads();
    }
    int rs = wbeg + s[tid] - c;  // exclusive within window
    cur[tid] = rs;
    int node = (p << 8) + tid;
    if (node < n) {
        rowstart[node] = rs;
        dinv[node] = rsqrtf((float)c + 1.0f);  // +1 self loop
    }
    if (p == 0 && tid == 0) rowstart[n] = e;
    __syncthreads();
    for (int i = wbeg + tid; i < wend; i += 256) {
        unsigned u = pairs[i];
        int pos = atomicAdd(&cur[u >> 16], 1);
        csr[pos] = (int)(u & 0xFFFFu);
    }
}

// h2_bf = bf16( a1b @ W2 ); A is pre-activated bf16 (bias1+relu fused upstream)
__global__ __launch_bounds__(256) void k_mgemm2(const unsigned short* __restrict__ a1b,
                                                const float* __restrict__ W2,
                                                unsigned short* __restrict__ h2_bf, int n) {
    __shared__ float ws[64 * 17];
    int tid = threadIdx.x;
    for (int i = tid; i < 64 * 16; i += 256) {
        int k = i >> 4, c = i & 15;
        ws[k * 17 + c] = W2[i];
    }
    __syncthreads();
    int lane = tid & 63, wv = tid >> 6;
    int rt = blockIdx.x * 64 + wv * 16;
    int r = lane & 15, g = lane >> 4;
    int row = rt + r;
    int rowc = row < n ? row : n - 1;
    const unsigned short* ap = a1b + (size_t)rowc * F1 + g * 8;
    bf16x8 ah[2];
    ah[0] = *(const bf16x8*)(ap);
    ah[1] = *(const bf16x8*)(ap + 32);
    bf16x8 bh[2], bl[2];
#pragma unroll
    for (int kb = 0; kb < 2; ++kb) {
        float v[8];
#pragma unroll
        for (int i = 0; i < 8; ++i)
            v[i] = ws[(kb * 32 + g * 8 + i) * 17 + r];
        cvt8(v, bh[kb], bl[kb]);
    }
    f32x4 acc = {0.f, 0.f, 0.f, 0.f};
#pragma unroll
    for (int kb = 0; kb < 2; ++kb) {
        acc = __builtin_amdgcn_mfma_f32_16x16x32_bf16(ah[kb], bh[kb], acc, 0, 0, 0);
        acc = __builtin_amdgcn_mfma_f32_16x16x32_bf16(ah[kb], bl[kb], acc, 0, 0, 0);
    }
#pragma unroll
    for (int j = 0; j < 4; ++j) {
        int orow = rt + g * 4 + j;
        if (orow < n) h2_bf[(size_t)orow * F2 + r] = f2bf(acc[j]);
    }
}

// ---------------- Aggregation (gather, bf16 tables, f32 accumulate) ----------------
// Wave layout: 8 edge-slots x 8 feat-octets (L1) / 32 slots x 2 octets (L2).
// Each lane gathers u16x8 (16B). Dead slots: dv=0 (w=0), idx=0 (cached row 0).

// layer-1 aggregation; epilogue fuses +b1, relu, bf16 store (A-operand of gemm2)
__global__ __launch_bounds__(256) void k_agg64(const int* __restrict__ rowstart,
                                               const int* __restrict__ csr,
                                               const float* __restrict__ dinv,
                                               const unsigned short* __restrict__ hb,
                                               const float* __restrict__ b1,
                                               unsigned short* __restrict__ a1b, int n) {
    int lane = threadIdx.x & 63, wv = threadIdx.x >> 6;
    int node = blockIdx.x * 4 + wv;
    if (node >= n) return;
    int g = lane >> 3, q = lane & 7;   // 8 edge slots x 8 feat-octets
    float di = dinv[node];
    float acc[8];
#pragma unroll
    for (int j = 0; j < 8; ++j) acc[j] = 0.f;
    int beg = rowstart[node], end = rowstart[node + 1];
    for (int base = beg; base < end; base += 64) {
        int k = base + lane;
        int idx = (k < end) ? csr[k] : 0;
        float dv = (k < end) ? dinv[idx] : 0.0f;
        int m = end - base;  // >0; slots >= m masked via dv=0
        if (m <= 32) {
#pragma unroll
            for (int i = 0; i < 4; ++i) {
                int slot = i * 8 + g;
                int s = __shfl(idx, slot, 64);
                float w = __shfl(dv, slot, 64);
                u16x8 u = *(const u16x8*)(hb + (size_t)s * F1 + q * 8);
#pragma unroll
                for (int j = 0; j < 8; ++j) acc[j] = fmaf(w, bf2f(u[j]), acc[j]);
            }
        } else {
#pragma unroll
            for (int i = 0; i < 8; ++i) {
                int slot = i * 8 + g;
                int s = __shfl(idx, slot, 64);
                float w = __shfl(dv, slot, 64);
                u16x8 u = *(const u16x8*)(hb + (size_t)s * F1 + q * 8);
#pragma unroll
                for (int j = 0; j < 8; ++j) acc[j] = fmaf(w, bf2f(u[j]), acc[j]);
            }
        }
    }
#pragma unroll
    for (int off = 8; off <= 32; off <<= 1)
#pragma unroll
        for (int j = 0; j < 8; ++j) acc[j] += __shfl_xor(acc[j], off, 64);
    if (g == 0) {
        u16x8 su = *(const u16x8*)(hb + (size_t)node * F1 + q * 8);
        float bl[8];
        *(float4*)&bl[0] = *(const float4*)(b1 + q * 8);
        *(float4*)&bl[4] = *(const float4*)(b1 + q * 8 + 4);
        float d2 = di * di;
        u16x8 rv;
#pragma unroll
        for (int j = 0; j < 8; ++j) {
            float o = fmaxf(fmaf(di, acc[j], fmaf(d2, bf2f(su[j]), bl[j])), 0.f);
            rv[j] = f2bf(o);
        }
        *(u16x8*)(a1b + (size_t)node * F1 + q * 8) = rv;
    }
}

// layer-2 aggregation + b2 + log-softmax; 32 edge slots x 2 feat-octets
__global__ __launch_bounds__(256) void k_agg16(const int* __restrict__ rowstart,
                                               const int* __restrict__ csr,
                                               const float* __restrict__ dinv,
                                               const unsigned short* __restrict__ h2b,
                                               const float* __restrict__ b2,
                                               float* __restrict__ out, int n) {
    int lane = threadIdx.x & 63, wv = threadIdx.x >> 6;
    int node = blockIdx.x * 4 + wv;
    if (node >= n) return;
    int g = lane >> 1, q = lane & 1;   // 32 edge slots x 2 feat-octets
    float di = dinv[node];
    float acc[8];
#pragma unroll
    for (int j = 0; j < 8; ++j) acc[j] = 0.f;
    int beg = rowstart[node], end = rowstart[node + 1];
    for (int base = beg; base < end; base += 64) {
        int k = base + lane;
        int idx = (k < end) ? csr[k] : 0;
        float dv = (k < end) ? dinv[idx] : 0.0f;
        int m = end - base;
        if (m <= 32) {
            int slot = g;
            int s = __shfl(idx, slot, 64);
            float w = __shfl(dv, slot, 64);
            u16x8 u = *(const u16x8*)(h2b + (size_t)s * F2 + q * 8);
#pragma unroll
            for (int j = 0; j < 8; ++j) acc[j] = fmaf(w, bf2f(u[j]), acc[j]);
        } else {
#pragma unroll
            for (int i = 0; i < 2; ++i) {
                int slot = i * 32 + g;
                int s = __shfl(idx, slot, 64);
                float w = __shfl(dv, slot, 64);
                u16x8 u = *(const u16x8*)(h2b + (size_t)s * F2 + q * 8);
#pragma unroll
                for (int j = 0; j < 8; ++j) acc[j] = fmaf(w, bf2f(u[j]), acc[j]);
            }
        }
    }
#pragma unroll
    for (int off = 2; off <= 32; off <<= 1)
#pragma unroll
        for (int j = 0; j < 8; ++j) acc[j] += __shfl_xor(acc[j], off, 64);
    // self-loop + bias (lanes sharing q identical)
    u16x8 su = *(const u16x8*)(h2b + (size_t)node * F2 + q * 8);
    float bl[8];
    *(float4*)&bl[0] = *(const float4*)(b2 + q * 8);
    *(float4*)&bl[4] = *(const float4*)(b2 + q * 8 + 4);
    float d2 = di * di;
    float vv[8];
#pragma unroll
    for (int j = 0; j < 8; ++j)
        vv[j] = fmaf(di, acc[j], fmaf(d2, bf2f(su[j]), bl[j]));
    // log-softmax across 16 feats = 8 local + partner lane (q bit = lane bit 0)
    float mr = vv[0];
#pragma unroll
    for (int j = 1; j < 8; ++j) mr = fmaxf(mr, vv[j]);
    mr = fmaxf(mr, __shfl_xor(mr, 1, 64));
    float sm = 0.f;
#pragma unroll
    for (int j = 0; j < 8; ++j) sm += expf(vv[j] - mr);
    sm += __shfl_xor(sm, 1, 64);
    float l = mr + logf(sm);
    if (g == 0) {
        float o[8];
#pragma unroll
        for (int j = 0; j < 8; ++j) o[j] = vv[j] - l;
        float* op = out + (size_t)node * F2 + q * 8;
        *(float4*)op = *(float4*)&o[0];
        *(float4*)(op + 4) = *(float4*)&o[4];
    }
}

extern "C" void kernel_launch(void* const* d_in, const int* in_sizes, int n_in,
                              void* d_out, int out_size, void* d_ws, size_t ws_size,
                              hipStream_t stream) {
    const float* x  = (const float*)d_in[0];
    const int*   ei = (const int*)d_in[1];
    const float* W1 = (const float*)d_in[2];
    const float* b1 = (const float*)d_in[3];
    const float* W2 = (const float*)d_in[4];
    const float* b2 = (const float*)d_in[5];
    float* out = (float*)d_out;

    const int n = in_sizes[0] / F1;   // 50000
    const int e = in_sizes[1] / 2;    // 800000
    const int e4 = e >> 2;
    const int* src = ei;
    const int* dst = ei + e;

    const int na = (n + 63) & ~63;
    const int npart = (n + 255) >> 8;  // 196 (<=256 for n<=65536)
    const int nb1 = (n + 63) / 64;     // mgemm1 blocks (782)

    // ws layout (4B units), disjoint regions (mgemm1 runs concurrently with part):
    // dinv[na] | rowstart[na+64] | ptotal[256] | csr[e] | h_bf[n*64 u16]
    // | a1b[n*64 u16] | hist[G*HP] | pgoff[G*HP] | pairs[e]
    float* dinv     = (float*)d_ws;
    int* rowstart   = (int*)(dinv + na);
    int* ptotal     = rowstart + na + 64;
    int* csr        = ptotal + 256;
    unsigned short* h_bf = (unsigned short*)(csr + ((e + 63) & ~63));
    unsigned short* a1b  = h_bf + (size_t)n * F1;
    int* hist       = (int*)(a1b + (size_t)n * F1);
    int* pgoff      = hist + G * HP;
    unsigned* pairs = (unsigned*)(pgoff + G * HP);
    unsigned short* h2_bf = h_bf;  // layer-2 reuse (h_bf dead after agg64)

    // ---- CSR build + layer-1 GEMM (stuffed) ----
    k_hist <<<G, 256, 0, stream>>>((const int4*)dst, dst, hist, e4, e);
    k_cscan<<<npart, 256, 0, stream>>>(hist, pgoff, ptotal);
    k_pm1  <<<nb1 + G, 256, 0, stream>>>(x, W1, h_bf,
                                         (const int4*)src, (const int4*)dst, src, dst,
                                         pgoff, ptotal, pairs, e4, e, npart, n, nb1);
    k_csr  <<<npart, 256, 0, stream>>>(pairs, ptotal, rowstart, dinv, csr, n, e, npart);

    // ---- layer 1 aggregation (fused bias1+relu+bf16) ----
    k_agg64<<<(n + 3) / 4, 256, 0, stream>>>(rowstart, csr, dinv, h_bf, b1, a1b, n);

    // ---- layer 2 ----
    k_mgemm2<<<(n + 63) / 64, 256, 0, stream>>>(a1b, W2, h2_bf, n);
    k_agg16<<<(n + 3) / 4, 256, 0, stream>>>(rowstart, csr, dinv, h2_bf, b2, out, n);
}